// Round 4
// baseline (256.190 us; speedup 1.0000x reference)
//
#include <hip/hip_runtime.h>
#include <hip/hip_bf16.h>

// B=2, T=4096, D=512, H=8, HD=64
#define BB 2
#define TT 4096
#define DD 512
#define HH 8
#define HD 64
#define M_TOT (BB*TT)          // 8192
#define N_QKV (3*DD)           // 1536

typedef __attribute__((ext_vector_type(8))) __bf16 bf16x8;
typedef __attribute__((ext_vector_type(4))) float f32x4;

#define MFMA16(a,b,c) __builtin_amdgcn_mfma_f32_16x16x32_bf16((a),(b),(c),0,0,0)

// softmax with FIXED shift: p = exp(s/8 - 8) = exp2(s*SCALE_L2E - SHIFT_L2E)
#define SCALE_L2E 0.18033688011112443f   // 0.125 * log2(e)
#define SHIFT_L2E 11.541560327111707f    // 8 * log2(e)

// RNE f32->bf16 (used in GEMM epilogues / cast)
static __device__ __forceinline__ unsigned short f2bf(float f) {
    union { float f; unsigned u; } v; v.f = f;
    return (unsigned short)((v.u + 0x8000u) >> 16);
}
// truncating f32->bf16 (attn path; bias cancels in softmax o/l ratio).
// (unsigned short)(u>>16) lets the compiler select ds_write_b16_d16_hi.
static __device__ __forceinline__ unsigned short f2bf_t(float f) {
    union { float f; unsigned u; } v; v.f = f;
    return (unsigned short)(v.u >> 16);
}

static __device__ __forceinline__ bf16x8 load8(const unsigned short* p) {
    bf16x8 v;
    __builtin_memcpy(&v, p, 16);
    return v;
}

static __device__ __forceinline__ bf16x8 ones_frag() {
    unsigned short u[8];
    #pragma unroll
    for (int i = 0; i < 8; i++) u[i] = 0x3F80;   // bf16 1.0
    bf16x8 v; __builtin_memcpy(&v, u, 16);
    return v;
}

#define GLDS(gp, lp) __builtin_amdgcn_global_load_lds( \
    (const __attribute__((address_space(1))) unsigned int*)(gp), \
    (__attribute__((address_space(3))) unsigned int*)(lp), 16, 0, 0)

// ---------------- fused cast fp32 -> bf16 for all three inputs ----------------
#define NX4 (M_TOT*DD/4)
#define NW4 (N_QKV*DD/4)
#define NO4 (DD*DD/4)
__global__ __launch_bounds__(256) void cast_all(
        const float* __restrict__ x, const float* __restrict__ wqkv,
        const float* __restrict__ wout,
        unsigned short* __restrict__ xb, unsigned short* __restrict__ wqkvb,
        unsigned short* __restrict__ woutb) {
    int i = blockIdx.x * 256 + threadIdx.x;
    const float* s; unsigned short* d; int j;
    if (i < NX4)            { s = x;    d = xb;    j = i; }
    else if (i < NX4 + NW4) { s = wqkv; d = wqkvb; j = i - NX4; }
    else                    { s = wout; d = woutb; j = i - NX4 - NW4; }
    float4 f = ((const float4*)s)[j];
    ushort4 o;
    o.x = f2bf(f.x); o.y = f2bf(f.y); o.z = f2bf(f.z); o.w = f2bf(f.w);
    ((ushort4*)d)[j] = o;
}

// ---------------- QKV GEMM: [8192,512] x [1536,512]^T, LDS-staged, BK=64 ----------------
__global__ __launch_bounds__(256) void qkv_gemm(
        const unsigned short* __restrict__ xb,
        const unsigned short* __restrict__ wb,
        unsigned short* __restrict__ qb,
        unsigned short* __restrict__ kb,
        unsigned short* __restrict__ vtb) {
    __shared__ unsigned short As[128 * 64];
    __shared__ unsigned short Bs[128 * 64];
    int tid = threadIdx.x;
    int w = tid >> 6, lane = tid & 63;
    int lrow = lane & 15, quad = lane >> 4;
    int bn = blockIdx.x % (N_QKV / 128);      // 12
    int bm = blockIdx.x / (N_QKV / 128);
    int m0 = bm * 128, n0 = bn * 128;
    int wm = w >> 1, wn = w & 1;

    f32x4 c[4][4];
    #pragma unroll
    for (int i = 0; i < 4; i++)
        #pragma unroll
        for (int j = 0; j < 4; j++) c[i][j] = (f32x4){0.f, 0.f, 0.f, 0.f};

    for (int k0 = 0; k0 < DD; k0 += 64) {
        // stage A,B tiles (128x64 each): 1024 chunks of 16B, 4 per thread per tile
        #pragma unroll
        for (int j = 0; j < 4; j++) {
            int ch = j * 256 + tid;
            int row = ch >> 3, kc = ch & 7;
            GLDS(xb + (size_t)(m0 + row) * DD + k0 + kc * 8,
                 (char*)As + (size_t)(j * 256 + w * 64) * 16);
        }
        #pragma unroll
        for (int j = 0; j < 4; j++) {
            int ch = j * 256 + tid;
            int row = ch >> 3, kc = ch & 7;
            GLDS(wb + (size_t)(n0 + row) * DD + k0 + kc * 8,
                 (char*)Bs + (size_t)(j * 256 + w * 64) * 16);
        }
        __syncthreads();
        #pragma unroll
        for (int kc = 0; kc < 2; kc++) {
            bf16x8 a[4], b[4];
            #pragma unroll
            for (int mf = 0; mf < 4; mf++)
                a[mf] = load8(&As[(wm * 64 + mf * 16 + lrow) * 64 + kc * 32 + quad * 8]);
            #pragma unroll
            for (int nf = 0; nf < 4; nf++)
                b[nf] = load8(&Bs[(wn * 64 + nf * 16 + lrow) * 64 + kc * 32 + quad * 8]);
            #pragma unroll
            for (int mf = 0; mf < 4; mf++)
                #pragma unroll
                for (int nf = 0; nf < 4; nf++)
                    c[mf][nf] = MFMA16(a[mf], b[nf], c[mf][nf]);
        }
        __syncthreads();
    }

    int m0w = m0 + wm * 64, n0w = n0 + wn * 64;
    int which = n0w >> 9;            // uniform per wave
    int h = (n0w & 511) >> 6;        // uniform per wave
    #pragma unroll
    for (int mf = 0; mf < 4; mf++) {
        #pragma unroll
        for (int r = 0; r < 4; r++) {
            int m = m0w + mf * 16 + quad * 4 + r;
            int t = m & (TT - 1), bi = m >> 12;
            size_t hb = (size_t)(bi * HH + h) * TT + t;
            #pragma unroll
            for (int nf = 0; nf < 4; nf++) {
                int d = nf * 16 + lrow;
                unsigned short val = f2bf(c[mf][nf][r]);
                if (which == 0)      qb[hb * HD + d] = val;
                else if (which == 1) kb[hb * HD + d] = val;
                else                 vtb[((size_t)(bi * HH + h) * HD + d) * TT + t] = val;
            }
        }
    }
}

// ---------------- Flash attention (causal, fixed-shift softmax) ----------------
// Paired q-tiles (p, 63-p): every block = exactly 65 kt-units.
// 6 waves split kt 6-ways (10.8-11 units/wave); tree-combine through LDS.
__global__ __launch_bounds__(384, 3) void attn_kernel(
        const unsigned short* __restrict__ qb,
        const unsigned short* __restrict__ kb,
        const unsigned short* __restrict__ vtb,
        unsigned short* __restrict__ attnb) {
    __shared__ union {
        unsigned short p[6][64][68];   // per-wave P tile (52.2 KB)
        float c[3][64][66];            // combine buffers (50.7 KB) — used after barrier
    } sm;

    int w = threadIdx.x >> 6;                    // 0..5
    int lane = threadIdx.x & 63;
    int lrow = lane & 15, quad = lane >> 4;
    int bh = blockIdx.x & 15;
    int pr = blockIdx.x >> 4;                    // 0..31
    int bi = bh >> 3, h = bh & 7;

    const unsigned short* qh = qb + (size_t)bh * TT * HD;
    const unsigned short* kh = kb + (size_t)bh * TT * HD;
    const unsigned short* vth = vtb + (size_t)bh * HD * TT;
    bf16x8 ones = ones_frag();

    for (int half = 0; half < 2; half++) {
        int qt = half ? (63 - pr) : pr;
        int q0 = qt * 64;

        bf16x8 qf[4][2];
        #pragma unroll
        for (int mf = 0; mf < 4; mf++) {
            const unsigned short* qp = qh + (q0 + mf * 16 + lrow) * HD + quad * 8;
            qf[mf][0] = load8(qp);
            qf[mf][1] = load8(qp + 32);
        }

        f32x4 o[4][4];
        f32x4 l[4];
        #pragma unroll
        for (int i = 0; i < 4; i++) {
            l[i] = (f32x4){0.f, 0.f, 0.f, 0.f};
            #pragma unroll
            for (int j = 0; j < 4; j++) o[i][j] = (f32x4){0.f, 0.f, 0.f, 0.f};
        }

        for (int kt = w; kt <= qt; kt += 6) {
            int kbase = kt * 64;
            bool diag = (kt == qt);
            // S = Q.K^T -> exp -> P into LDS (A-layout transform)
            #pragma unroll
            for (int nf = 0; nf < 4; nf++) {
                const unsigned short* kp = kh + (kbase + nf * 16 + lrow) * HD + quad * 8;
                bf16x8 kf0 = load8(kp);
                bf16x8 kf1 = load8(kp + 32);
                #pragma unroll
                for (int mf = 0; mf < 4; mf++) {
                    if (diag && nf > mf) {   // fully-masked sub-tile
                        #pragma unroll
                        for (int r = 0; r < 4; r++)
                            sm.p[w][mf * 16 + quad * 4 + r][nf * 16 + lrow] = 0;
                    } else {
                        f32x4 s = {0.f, 0.f, 0.f, 0.f};
                        s = MFMA16(qf[mf][0], kf0, s);
                        s = MFMA16(qf[mf][1], kf1, s);
                        #pragma unroll
                        for (int r = 0; r < 4; r++) {
                            float p = __builtin_amdgcn_exp2f(s[r] * SCALE_L2E - SHIFT_L2E);
                            if (diag && nf == mf && lrow > quad * 4 + r) p = 0.f;
                            sm.p[w][mf * 16 + quad * 4 + r][nf * 16 + lrow] = f2bf_t(p);
                        }
                    }
                }
            }
            // V fragments (B-operand from V^T: rows d, contiguous along t)
            bf16x8 vf[4][2];
            #pragma unroll
            for (int nfd = 0; nfd < 4; nfd++) {
                const unsigned short* vp = vth + (nfd * 16 + lrow) * TT + kbase + quad * 8;
                vf[nfd][0] = load8(vp);
                vf[nfd][1] = load8(vp + 32);
            }
            // PV + rowsum (ones-MFMA)
            #pragma unroll
            for (int mf = 0; mf < 4; mf++) {
                bf16x8 pa0, pa1;
                __builtin_memcpy(&pa0, &sm.p[w][mf * 16 + lrow][quad * 8], 16);
                __builtin_memcpy(&pa1, &sm.p[w][mf * 16 + lrow][32 + quad * 8], 16);
                l[mf] = MFMA16(pa0, ones, l[mf]);
                l[mf] = MFMA16(pa1, ones, l[mf]);
                #pragma unroll
                for (int nfd = 0; nfd < 4; nfd++) {
                    o[mf][nfd] = MFMA16(pa0, vf[nfd][0], o[mf][nfd]);
                    o[mf][nfd] = MFMA16(pa1, vf[nfd][1], o[mf][nfd]);
                }
            }
        }

        // -------- combine 6 waves' partials (pure sums) --------
        __syncthreads();                       // all waves done with P tiles
        if (w >= 3) {                          // round 1: waves 3,4,5 -> bufs 0,1,2
            int cb = w - 3;
            #pragma unroll
            for (int mf = 0; mf < 4; mf++)
                #pragma unroll
                for (int r = 0; r < 4; r++) {
                    int row = mf * 16 + quad * 4 + r;
                    #pragma unroll
                    for (int nfd = 0; nfd < 4; nfd++)
                        sm.c[cb][row][nfd * 16 + lrow] = o[mf][nfd][r];
                    if (lrow == 0) sm.c[cb][row][64] = l[mf][r];
                }
        }
        __syncthreads();
        if (w < 3) {                           // round 2: waves 0,1,2 add
            #pragma unroll
            for (int mf = 0; mf < 4; mf++)
                #pragma unroll
                for (int r = 0; r < 4; r++) {
                    int row = mf * 16 + quad * 4 + r;
                    #pragma unroll
                    for (int nfd = 0; nfd < 4; nfd++)
                        sm.c[w][row][nfd * 16 + lrow] += o[mf][nfd][r];
                    if (lrow == 0) sm.c[w][row][64] += l[mf][r];
                }
        }
        __syncthreads();
        // round 3: waves 0..3 normalize + store 16-row slices
        if (w < 4) {
            #pragma unroll
            for (int r = 0; r < 4; r++) {
                int row = w * 16 + quad * 4 + r;
                float lsum = sm.c[0][row][64] + sm.c[1][row][64] + sm.c[2][row][64];
                float inv = 1.0f / lsum;
                int t = q0 + row;
                size_t base = ((size_t)(bi * TT + t)) * DD + h * HD;
                #pragma unroll
                for (int nfd = 0; nfd < 4; nfd++) {
                    int col = nfd * 16 + lrow;
                    float v = (sm.c[0][row][col] + sm.c[1][row][col] + sm.c[2][row][col]) * inv;
                    attnb[base + col] = f2bf_t(v);
                }
            }
        }
        __syncthreads();                       // before next half reuses sm
    }
}

// ---------------- out projection: [8192,512] x [512,512]^T -> fp32, BK=64 ----------------
__global__ __launch_bounds__(256) void proj_gemm(
        const unsigned short* __restrict__ ab,
        const unsigned short* __restrict__ wb,
        float* __restrict__ out) {
    __shared__ unsigned short As[128 * 64];
    __shared__ unsigned short Bs[128 * 64];
    int tid = threadIdx.x;
    int w = tid >> 6, lane = tid & 63;
    int lrow = lane & 15, quad = lane >> 4;
    int bn = blockIdx.x % (DD / 128);         // 4
    int bm = blockIdx.x / (DD / 128);
    int m0 = bm * 128, n0 = bn * 128;
    int wm = w >> 1, wn = w & 1;

    f32x4 c[4][4];
    #pragma unroll
    for (int i = 0; i < 4; i++)
        #pragma unroll
        for (int j = 0; j < 4; j++) c[i][j] = (f32x4){0.f, 0.f, 0.f, 0.f};

    for (int k0 = 0; k0 < DD; k0 += 64) {
        #pragma unroll
        for (int j = 0; j < 4; j++) {
            int ch = j * 256 + tid;
            int row = ch >> 3, kc = ch & 7;
            GLDS(ab + (size_t)(m0 + row) * DD + k0 + kc * 8,
                 (char*)As + (size_t)(j * 256 + w * 64) * 16);
        }
        #pragma unroll
        for (int j = 0; j < 4; j++) {
            int ch = j * 256 + tid;
            int row = ch >> 3, kc = ch & 7;
            GLDS(wb + (size_t)(n0 + row) * DD + k0 + kc * 8,
                 (char*)Bs + (size_t)(j * 256 + w * 64) * 16);
        }
        __syncthreads();
        #pragma unroll
        for (int kc = 0; kc < 2; kc++) {
            bf16x8 a[4], b[4];
            #pragma unroll
            for (int mf = 0; mf < 4; mf++)
                a[mf] = load8(&As[(wm * 64 + mf * 16 + lrow) * 64 + kc * 32 + quad * 8]);
            #pragma unroll
            for (int nf = 0; nf < 4; nf++)
                b[nf] = load8(&Bs[(wn * 64 + nf * 16 + lrow) * 64 + kc * 32 + quad * 8]);
            #pragma unroll
            for (int mf = 0; mf < 4; mf++)
                #pragma unroll
                for (int nf = 0; nf < 4; nf++)
                    c[mf][nf] = MFMA16(a[mf], b[nf], c[mf][nf]);
        }
        __syncthreads();
    }

    #pragma unroll
    for (int mf = 0; mf < 4; mf++) {
        #pragma unroll
        for (int r = 0; r < 4; r++) {
            int m = m0 + wm * 64 + mf * 16 + quad * 4 + r;
            #pragma unroll
            for (int nf = 0; nf < 4; nf++) {
                int n = n0 + wn * 64 + nf * 16 + lrow;
                out[(size_t)m * DD + n] = c[mf][nf][r];
            }
        }
    }
}

extern "C" void kernel_launch(void* const* d_in, const int* in_sizes, int n_in,
                              void* d_out, int out_size, void* d_ws, size_t ws_size,
                              hipStream_t stream) {
    const float* x    = (const float*)d_in[0];   // [2,4096,512]
    const float* wqkv = (const float*)d_in[1];   // [1536,512]
    const float* wout = (const float*)d_in[2];   // [512,512]
    float* out = (float*)d_out;                  // [2,4096,512]

    char* ws = (char*)d_ws;
    unsigned short* xb    = (unsigned short*)ws; ws += (size_t)M_TOT * DD * 2;
    unsigned short* wqkvb = (unsigned short*)ws; ws += (size_t)N_QKV * DD * 2;
    unsigned short* woutb = (unsigned short*)ws; ws += (size_t)DD * DD * 2;
    unsigned short* qb    = (unsigned short*)ws; ws += (size_t)BB * HH * TT * HD * 2;
    unsigned short* kb    = (unsigned short*)ws; ws += (size_t)BB * HH * TT * HD * 2;
    unsigned short* vtb   = (unsigned short*)ws; ws += (size_t)BB * HH * HD * TT * 2;
    unsigned short* attnb = (unsigned short*)ws; ws += (size_t)M_TOT * DD * 2;

    cast_all<<<(NX4 + NW4 + NO4) / 256, 256, 0, stream>>>(x, wqkv, wout, xb, wqkvb, woutb);

    qkv_gemm<<<(M_TOT / 128) * (N_QKV / 128), 256, 0, stream>>>(xb, wqkvb, qb, kb, vtb);

    // 16 bh x 32 tile-pairs = 512 blocks, all equal work (65 kt-units), 6 waves each
    attn_kernel<<<512, 384, 0, stream>>>(qb, kb, vtb, attnb);

    proj_gemm<<<(M_TOT / 128) * (DD / 128), 256, 0, stream>>>(attnb, woutb, out);
}

// Round 5
// 202.018 us; speedup vs baseline: 1.2682x; 1.2682x over previous
//
#include <hip/hip_runtime.h>
#include <hip/hip_bf16.h>

// B=2, T=4096, D=512, H=8, HD=64
#define BB 2
#define TT 4096
#define DD 512
#define HH 8
#define HD 64
#define M_TOT (BB*TT)          // 8192
#define N_QKV (3*DD)           // 1536

typedef __attribute__((ext_vector_type(8))) __bf16 bf16x8;
typedef __attribute__((ext_vector_type(4))) float f32x4;

#define MFMA16(a,b,c) __builtin_amdgcn_mfma_f32_16x16x32_bf16((a),(b),(c),0,0,0)

// softmax with FIXED shift: p = exp(s/8 - 8) = exp2(s*SCALE_L2E - SHIFT_L2E)
#define SCALE_L2E 0.18033688011112443f   // 0.125 * log2(e)
#define SHIFT_L2E 11.541560327111707f    // 8 * log2(e)

// RNE-ish f32->bf16
static __device__ __forceinline__ unsigned short f2bf(float f) {
    union { float f; unsigned u; } v; v.f = f;
    return (unsigned short)((v.u + 0x8000u) >> 16);
}
// truncating f32->bf16 (attn path; bias cancels in softmax o/l ratio)
static __device__ __forceinline__ unsigned short f2bf_t(float f) {
    union { float f; unsigned u; } v; v.f = f;
    return (unsigned short)(v.u >> 16);
}

static __device__ __forceinline__ bf16x8 load8(const unsigned short* p) {
    bf16x8 v;
    __builtin_memcpy(&v, p, 16);
    return v;
}

static __device__ __forceinline__ bf16x8 ones_frag() {
    unsigned short u[8];
    #pragma unroll
    for (int i = 0; i < 8; i++) u[i] = 0x3F80;   // bf16 1.0
    bf16x8 v; __builtin_memcpy(&v, u, 16);
    return v;
}

#define GLDS(gp, lp) __builtin_amdgcn_global_load_lds( \
    (const __attribute__((address_space(1))) unsigned int*)(gp), \
    (__attribute__((address_space(3))) unsigned int*)(lp), 16, 0, 0)

// ---------------- fused cast fp32 -> bf16 for all three inputs ----------------
#define NX4 (M_TOT*DD/4)
#define NW4 (N_QKV*DD/4)
#define NO4 (DD*DD/4)
__global__ __launch_bounds__(256) void cast_all(
        const float* __restrict__ x, const float* __restrict__ wqkv,
        const float* __restrict__ wout,
        unsigned short* __restrict__ xb, unsigned short* __restrict__ wqkvb,
        unsigned short* __restrict__ woutb) {
    int i = blockIdx.x * 256 + threadIdx.x;
    const float* s; unsigned short* d; int j;
    if (i < NX4)            { s = x;    d = xb;    j = i; }
    else if (i < NX4 + NW4) { s = wqkv; d = wqkvb; j = i - NX4; }
    else                    { s = wout; d = woutb; j = i - NX4 - NW4; }
    float4 f = ((const float4*)s)[j];
    ushort4 o;
    o.x = f2bf(f.x); o.y = f2bf(f.y); o.z = f2bf(f.z); o.w = f2bf(f.w);
    ((ushort4*)d)[j] = o;
}

// ---------------- QKV GEMM: [8192,512] x [1536,512]^T, LDS-staged, BK=32 ----------------
// V output transposed via per-wave LDS tile -> coalesced 16B stores
__global__ __launch_bounds__(256) void qkv_gemm(
        const unsigned short* __restrict__ xb,
        const unsigned short* __restrict__ wb,
        unsigned short* __restrict__ qb,
        unsigned short* __restrict__ kb,
        unsigned short* __restrict__ vtb) {
    __shared__ union {
        struct { unsigned short As[128 * 32]; unsigned short Bs[128 * 32]; } g;
        unsigned short vt[4][64][72];   // per-wave V-transpose tile (36.9 KB)
    } sm;
    int tid = threadIdx.x;
    int w = tid >> 6, lane = tid & 63;
    int lrow = lane & 15, quad = lane >> 4;
    int bn = blockIdx.x % (N_QKV / 128);      // 12
    int bm = blockIdx.x / (N_QKV / 128);
    int m0 = bm * 128, n0 = bn * 128;
    int wm = w >> 1, wn = w & 1;

    f32x4 c[4][4];
    #pragma unroll
    for (int i = 0; i < 4; i++)
        #pragma unroll
        for (int j = 0; j < 4; j++) c[i][j] = (f32x4){0.f, 0.f, 0.f, 0.f};

    for (int k0 = 0; k0 < DD; k0 += 32) {
        // stage A,B tiles (128x32 each) via direct-to-LDS, 16B/lane
        #pragma unroll
        for (int j = 0; j < 2; j++) {
            int ch = j * 256 + tid;
            int row = ch >> 2, kc = ch & 3;
            GLDS(xb + (size_t)(m0 + row) * DD + k0 + kc * 8,
                 (char*)sm.g.As + (size_t)(j * 256 + w * 64) * 16);
        }
        #pragma unroll
        for (int j = 0; j < 2; j++) {
            int ch = j * 256 + tid;
            int row = ch >> 2, kc = ch & 3;
            GLDS(wb + (size_t)(n0 + row) * DD + k0 + kc * 8,
                 (char*)sm.g.Bs + (size_t)(j * 256 + w * 64) * 16);
        }
        __syncthreads();
        bf16x8 a[4], b[4];
        #pragma unroll
        for (int mf = 0; mf < 4; mf++) a[mf] = load8(&sm.g.As[(wm * 64 + mf * 16 + lrow) * 32 + quad * 8]);
        #pragma unroll
        for (int nf = 0; nf < 4; nf++) b[nf] = load8(&sm.g.Bs[(wn * 64 + nf * 16 + lrow) * 32 + quad * 8]);
        #pragma unroll
        for (int mf = 0; mf < 4; mf++)
            #pragma unroll
            for (int nf = 0; nf < 4; nf++)
                c[mf][nf] = MFMA16(a[mf], b[nf], c[mf][nf]);
        __syncthreads();
    }

    int m0w = m0 + wm * 64, n0w = n0 + wn * 64;
    int which = n0w >> 9;            // uniform per block (0=q 1=k 2=v)
    int h = (n0w & 511) >> 6;        // uniform per wave
    if (which < 2) {
        unsigned short* dst = (which == 0) ? qb : kb;
        #pragma unroll
        for (int mf = 0; mf < 4; mf++) {
            #pragma unroll
            for (int r = 0; r < 4; r++) {
                int m = m0w + mf * 16 + quad * 4 + r;
                int t = m & (TT - 1), bi = m >> 12;
                size_t hb = (size_t)(bi * HH + h) * TT + t;
                #pragma unroll
                for (int nf = 0; nf < 4; nf++) {
                    int d = nf * 16 + lrow;
                    dst[hb * HD + d] = f2bf(c[mf][nf][r]);
                }
            }
        }
    } else {
        // scatter c^T into per-wave LDS tile: vt[d][t_local]
        #pragma unroll
        for (int mf = 0; mf < 4; mf++)
            #pragma unroll
            for (int r = 0; r < 4; r++)
                #pragma unroll
                for (int nf = 0; nf < 4; nf++)
                    sm.vt[w][nf * 16 + lrow][mf * 16 + quad * 4 + r] = f2bf(c[mf][nf][r]);
        int bi = m0w >> 12, t0 = m0w & (TT - 1);
        size_t hb = (size_t)(bi * HH + h) * HD;
        #pragma unroll
        for (int i = 0; i < 8; i++) {
            int d = i * 8 + (lane >> 3);
            int tc = (lane & 7) * 8;
            bf16x8 v;
            __builtin_memcpy(&v, &sm.vt[w][d][tc], 16);
            __builtin_memcpy(vtb + (hb + d) * TT + t0 + tc, &v, 16);
        }
    }
}

// ---------------- Flash attention (causal, fixed-shift softmax) ----------------
// Paired q-tiles (p, 63-p) = 65 kt-units; split across 2 blocks x 4 waves by
// kt residue mod 8 (rotated by pr). fp32 partial (o,l) -> global; norm kernel combines.
__global__ __launch_bounds__(256) void attn_kernel(
        const unsigned short* __restrict__ qb,
        const unsigned short* __restrict__ kb,
        const unsigned short* __restrict__ vtb,
        float* __restrict__ ows, float* __restrict__ lws) {
    __shared__ union {
        unsigned short p[4][64][68];   // per-wave P tile (34.8 KB)
        float c[2][64][66];            // combine buffers (33.8 KB) — after barrier
    } sm;

    int w = threadIdx.x >> 6;
    int lane = threadIdx.x & 63;
    int lrow = lane & 15, quad = lane >> 4;
    int bh = blockIdx.x & 15;
    int pr = (blockIdx.x >> 4) & 31;             // pair index 0..31
    int seg = blockIdx.x >> 9;                   // 0,1

    const unsigned short* qh = qb + (size_t)bh * TT * HD;
    const unsigned short* kh = kb + (size_t)bh * TT * HD;
    const unsigned short* vth = vtb + (size_t)bh * HD * TT;
    bf16x8 ones = ones_frag();

    int kres = (seg * 4 + w + pr) & 7;           // this wave's kt residue mod 8

    for (int half = 0; half < 2; half++) {
        int qt = half ? (63 - pr) : pr;
        int q0 = qt * 64;

        bf16x8 qf[4][2];
        #pragma unroll
        for (int mf = 0; mf < 4; mf++) {
            const unsigned short* qp = qh + (q0 + mf * 16 + lrow) * HD + quad * 8;
            qf[mf][0] = load8(qp);
            qf[mf][1] = load8(qp + 32);
        }

        f32x4 o[4][4];
        f32x4 l[4];
        #pragma unroll
        for (int i = 0; i < 4; i++) {
            l[i] = (f32x4){0.f, 0.f, 0.f, 0.f};
            #pragma unroll
            for (int j = 0; j < 4; j++) o[i][j] = (f32x4){0.f, 0.f, 0.f, 0.f};
        }

        for (int kt = kres; kt <= qt; kt += 8) {
            int kbase = kt * 64;
            bool diag = (kt == qt);
            // V fragments issued early (not needed until PV -> latency cover)
            bf16x8 vf[4][2];
            #pragma unroll
            for (int nfd = 0; nfd < 4; nfd++) {
                const unsigned short* vp = vth + (nfd * 16 + lrow) * TT + kbase + quad * 8;
                vf[nfd][0] = load8(vp);
                vf[nfd][1] = load8(vp + 32);
            }
            // S = Q.K^T -> exp -> P into LDS (A-layout transform)
            #pragma unroll
            for (int nf = 0; nf < 4; nf++) {
                const unsigned short* kp = kh + (kbase + nf * 16 + lrow) * HD + quad * 8;
                bf16x8 kf0 = load8(kp);
                bf16x8 kf1 = load8(kp + 32);
                #pragma unroll
                for (int mf = 0; mf < 4; mf++) {
                    if (diag && nf > mf) {   // fully-masked sub-tile
                        #pragma unroll
                        for (int r = 0; r < 4; r++)
                            sm.p[w][mf * 16 + quad * 4 + r][nf * 16 + lrow] = 0;
                    } else {
                        f32x4 sv = {0.f, 0.f, 0.f, 0.f};
                        sv = MFMA16(qf[mf][0], kf0, sv);
                        sv = MFMA16(qf[mf][1], kf1, sv);
                        #pragma unroll
                        for (int r = 0; r < 4; r++) {
                            float p = __builtin_amdgcn_exp2f(sv[r] * SCALE_L2E - SHIFT_L2E);
                            if (diag && nf == mf && lrow > quad * 4 + r) p = 0.f;
                            sm.p[w][mf * 16 + quad * 4 + r][nf * 16 + lrow] = f2bf_t(p);
                        }
                    }
                }
            }
            // PV + rowsum (ones-MFMA)
            #pragma unroll
            for (int mf = 0; mf < 4; mf++) {
                bf16x8 pa0, pa1;
                __builtin_memcpy(&pa0, &sm.p[w][mf * 16 + lrow][quad * 8], 16);
                __builtin_memcpy(&pa1, &sm.p[w][mf * 16 + lrow][32 + quad * 8], 16);
                l[mf] = MFMA16(pa0, ones, l[mf]);
                l[mf] = MFMA16(pa1, ones, l[mf]);
                #pragma unroll
                for (int nfd = 0; nfd < 4; nfd++) {
                    o[mf][nfd] = MFMA16(pa0, vf[nfd][0], o[mf][nfd]);
                    o[mf][nfd] = MFMA16(pa1, vf[nfd][1], o[mf][nfd]);
                }
            }
        }

        // -------- combine 4 waves' partials (pure sums) --------
        __syncthreads();                       // all waves done with P tiles
        if (w >= 2) {                          // round 1: waves 2,3 -> bufs 0,1
            int cb = w - 2;
            #pragma unroll
            for (int mf = 0; mf < 4; mf++)
                #pragma unroll
                for (int r = 0; r < 4; r++) {
                    int row = mf * 16 + quad * 4 + r;
                    #pragma unroll
                    for (int nfd = 0; nfd < 4; nfd++)
                        sm.c[cb][row][nfd * 16 + lrow] = o[mf][nfd][r];
                    if (lrow == 0) sm.c[cb][row][64] = l[mf][r];
                }
        }
        __syncthreads();
        if (w < 2) {                           // round 2: waves 0,1 add
            #pragma unroll
            for (int mf = 0; mf < 4; mf++)
                #pragma unroll
                for (int r = 0; r < 4; r++) {
                    int row = mf * 16 + quad * 4 + r;
                    #pragma unroll
                    for (int nfd = 0; nfd < 4; nfd++)
                        sm.c[w][row][nfd * 16 + lrow] += o[mf][nfd][r];
                    if (lrow == 0) sm.c[w][row][64] += l[mf][r];
                }
        }
        __syncthreads();
        // round 3: every wave stores a 16-row slice of the fp32 partial
        size_t tbase = ((size_t)(bh * 64 + qt) * 2 + seg) * 64;
        #pragma unroll
        for (int r = 0; r < 4; r++) {
            int row = w * 16 + quad * 4 + r;
            if (lrow == 0)
                lws[tbase + row] = sm.c[0][row][64] + sm.c[1][row][64];
            #pragma unroll
            for (int nfd = 0; nfd < 4; nfd++) {
                int col = nfd * 16 + lrow;
                ows[(tbase + row) * 64 + col] = sm.c[0][row][col] + sm.c[1][row][col];
            }
        }
        __syncthreads();                       // before next half reuses sm
    }
}

// ---------------- combine 2 segments, normalize, store bf16 ----------------
__global__ __launch_bounds__(256) void attn_norm(
        const float* __restrict__ ows, const float* __restrict__ lws,
        unsigned short* __restrict__ attnb) {
    int g = blockIdx.x;                 // tile = bh*64 + qt
    int bh = g >> 6, qt = g & 63;
    int bi = bh >> 3, h = bh & 7;
    int row = threadIdx.x >> 2, dg = threadIdx.x & 3;
    size_t r0 = ((size_t)g * 2 + 0) * 64 + row;
    size_t r1 = r0 + 64;
    float inv = 1.0f / (lws[r0] + lws[r1]);
    const float4* p0 = (const float4*)(ows + r0 * 64 + dg * 16);
    const float4* p1 = (const float4*)(ows + r1 * 64 + dg * 16);
    int t = qt * 64 + row;
    unsigned short* dst = attnb + ((size_t)(bi * TT + t)) * DD + h * HD + dg * 16;
    ushort4 outv[4];
    #pragma unroll
    for (int j = 0; j < 4; j++) {
        float4 a = p0[j], b = p1[j];
        outv[j].x = f2bf_t((a.x + b.x) * inv);
        outv[j].y = f2bf_t((a.y + b.y) * inv);
        outv[j].z = f2bf_t((a.z + b.z) * inv);
        outv[j].w = f2bf_t((a.w + b.w) * inv);
    }
    __builtin_memcpy(dst, outv, 32);
}

// ---------------- out projection: [8192,512] x [512,512]^T -> fp32, BK=32 ----------------
__global__ __launch_bounds__(256) void proj_gemm(
        const unsigned short* __restrict__ ab,
        const unsigned short* __restrict__ wb,
        float* __restrict__ out) {
    __shared__ unsigned short As[128 * 32];
    __shared__ unsigned short Bs[128 * 32];
    int tid = threadIdx.x;
    int w = tid >> 6, lane = tid & 63;
    int lrow = lane & 15, quad = lane >> 4;
    int bn = blockIdx.x % (DD / 128);         // 4
    int bm = blockIdx.x / (DD / 128);
    int m0 = bm * 128, n0 = bn * 128;
    int wm = w >> 1, wn = w & 1;

    f32x4 c[4][4];
    #pragma unroll
    for (int i = 0; i < 4; i++)
        #pragma unroll
        for (int j = 0; j < 4; j++) c[i][j] = (f32x4){0.f, 0.f, 0.f, 0.f};

    for (int k0 = 0; k0 < DD; k0 += 32) {
        #pragma unroll
        for (int j = 0; j < 2; j++) {
            int ch = j * 256 + tid;
            int row = ch >> 2, kc = ch & 3;
            GLDS(ab + (size_t)(m0 + row) * DD + k0 + kc * 8,
                 (char*)As + (size_t)(j * 256 + w * 64) * 16);
        }
        #pragma unroll
        for (int j = 0; j < 2; j++) {
            int ch = j * 256 + tid;
            int row = ch >> 2, kc = ch & 3;
            GLDS(wb + (size_t)(n0 + row) * DD + k0 + kc * 8,
                 (char*)Bs + (size_t)(j * 256 + w * 64) * 16);
        }
        __syncthreads();
        bf16x8 a[4], b[4];
        #pragma unroll
        for (int mf = 0; mf < 4; mf++) a[mf] = load8(&As[(wm * 64 + mf * 16 + lrow) * 32 + quad * 8]);
        #pragma unroll
        for (int nf = 0; nf < 4; nf++) b[nf] = load8(&Bs[(wn * 64 + nf * 16 + lrow) * 32 + quad * 8]);
        #pragma unroll
        for (int mf = 0; mf < 4; mf++)
            #pragma unroll
            for (int nf = 0; nf < 4; nf++)
                c[mf][nf] = MFMA16(a[mf], b[nf], c[mf][nf]);
        __syncthreads();
    }

    #pragma unroll
    for (int mf = 0; mf < 4; mf++) {
        #pragma unroll
        for (int r = 0; r < 4; r++) {
            int m = m0 + wm * 64 + mf * 16 + quad * 4 + r;
            #pragma unroll
            for (int nf = 0; nf < 4; nf++) {
                int n = n0 + wn * 64 + nf * 16 + lrow;
                out[(size_t)m * DD + n] = c[mf][nf][r];
            }
        }
    }
}

extern "C" void kernel_launch(void* const* d_in, const int* in_sizes, int n_in,
                              void* d_out, int out_size, void* d_ws, size_t ws_size,
                              hipStream_t stream) {
    const float* x    = (const float*)d_in[0];   // [2,4096,512]
    const float* wqkv = (const float*)d_in[1];   // [1536,512]
    const float* wout = (const float*)d_in[2];   // [512,512]
    float* out = (float*)d_out;                  // [2,4096,512]

    char* ws = (char*)d_ws;
    unsigned short* xb    = (unsigned short*)ws; ws += (size_t)M_TOT * DD * 2;
    unsigned short* wqkvb = (unsigned short*)ws; ws += (size_t)N_QKV * DD * 2;
    unsigned short* woutb = (unsigned short*)ws; ws += (size_t)DD * DD * 2;
    unsigned short* qb    = (unsigned short*)ws; ws += (size_t)BB * HH * TT * HD * 2;
    unsigned short* kb    = (unsigned short*)ws; ws += (size_t)BB * HH * TT * HD * 2;
    unsigned short* vtb   = (unsigned short*)ws; ws += (size_t)BB * HH * HD * TT * 2;
    unsigned short* attnb = (unsigned short*)ws; ws += (size_t)M_TOT * DD * 2;
    float* ows = (float*)ws; ws += (size_t)1024 * 2 * 64 * 64 * 4;   // 33.6 MB
    float* lws = (float*)ws; ws += (size_t)1024 * 2 * 64 * 4;        // 0.5 MB

    cast_all<<<(NX4 + NW4 + NO4) / 256, 256, 0, stream>>>(x, wqkv, wout, xb, wqkvb, woutb);

    qkv_gemm<<<(M_TOT / 128) * (N_QKV / 128), 256, 0, stream>>>(xb, wqkvb, qb, kb, vtb);

    // 16 bh x 32 pairs x 2 kt-segments = 1024 blocks, 4 waves each
    attn_kernel<<<1024, 256, 0, stream>>>(qb, kb, vtb, ows, lws);

    // one block per (bh, qt) tile
    attn_norm<<<1024, 256, 0, stream>>>(ows, lws, attnb);

    proj_gemm<<<(M_TOT / 128) * (DD / 128), 256, 0, stream>>>(attnb, woutb, out);
}